// Round 3
// baseline (377.239 us; speedup 1.0000x reference)
//
#include <hip/hip_runtime.h>
#include <hip/hip_bf16.h>

typedef unsigned short u16;
typedef float f32x4 __attribute__((ext_vector_type(4)));
typedef short s16x8 __attribute__((ext_vector_type(8)));

#define NB 4
#define NN 20000
#define NE 320000
#define ROWS (NB*NN)          // 80000

__device__ __forceinline__ float b2f(u16 u){
  union{unsigned int i; float f;} v; v.i = ((unsigned int)u)<<16; return v.f;
}
__device__ __forceinline__ u16 f2b(float f){
  __hip_bfloat16 h = __float2bfloat16(f);
  return __builtin_bit_cast(u16, h);
}

// ---------------- K0: zero-init scratch ----------------
__global__ void zero_kernel(float* deg, int* cnt, int* cursor, float* y_acc){
  int i = blockIdx.x*blockDim.x + threadIdx.x;
  if(i < NN){ deg[i]=0.f; cnt[i]=0; cursor[i]=0; }
  if(i < 256) y_acc[i]=0.f;
}

// ---------------- K1: degree + count histogram ----------------
__global__ void hist_kernel(const int* __restrict__ ei, const float* __restrict__ ew,
                            float* deg, int* cnt){
  int e = blockIdx.x*blockDim.x + threadIdx.x;
  if(e >= NE) return;
  int d = ei[NE + e];
  atomicAdd(&deg[d], ew[e]);
  atomicAdd(&cnt[d], 1);
}

// ---------------- K2: exclusive prefix sum of cnt -> row_off, + dinv ----------------
__global__ void scan_kernel(const int* __restrict__ cnt, int* row_off,
                            const float* __restrict__ deg, float* dinv){
  __shared__ int part[1024];
  int t = threadIdx.x;
  const int chunk = (NN + 1023)/1024; // 20
  int s0 = t*chunk;
  int local = 0;
  for(int i=0;i<chunk;i++){
    int idx=s0+i;
    if(idx<NN){
      local += cnt[idx];
      float d = deg[idx];
      dinv[idx] = (d > 0.f) ? rsqrtf(fmaxf(d, 1e-12f)) : 0.f;
    }
  }
  part[t] = local;
  __syncthreads();
  for(int off=1; off<1024; off<<=1){
    int v = (t>=off) ? part[t-off] : 0;
    __syncthreads();
    part[t] += v;
    __syncthreads();
  }
  int base = (t>0) ? part[t-1] : 0;
  for(int i=0;i<chunk;i++){ int idx=s0+i; if(idx<NN){ row_off[idx]=base; base += cnt[idx]; } }
  if(t==1023) row_off[NN] = part[1023];
}

// ---------------- K3: CSR fill (interleaved {src, norm}) ----------------
__global__ void fill_kernel(const int* __restrict__ ei, const float* __restrict__ ew,
                            const float* __restrict__ dinv, const int* __restrict__ row_off,
                            int* cursor, int2* csr_ent){
  int e = blockIdx.x*blockDim.x + threadIdx.x;
  if(e >= NE) return;
  int s = ei[e], d = ei[NE + e];
  float nr = dinv[s] * ew[e] * dinv[d];
  int p = row_off[d] + atomicAdd(&cursor[d], 1);
  int2 ent; ent.x = s; ent.y = __float_as_int(nr);
  csr_ent[p] = ent;
}

// ---------------- K4: prep — fuse weights + build MFMA B-fragments (single block) ----
// fused matrices (bf16, staged in LDS):
//   m=2g+0: Wg @ Lg_top   m=2g+1: Lg_bot       g in {z,r,h}
// cvec[g*64+j] = bg @ Lg_top + lbg
// frag item (m,s,t,lane): value[j] = mat_m[(s*32 + (lane>>4)*8 + j)*64 + t*16 + (lane&15)]
__global__ void __launch_bounds__(1024) prep_kernel(
    const float* Wz, const float* bz, const float* Lz, const float* lbz,
    const float* Wr, const float* br, const float* Lr, const float* lbr,
    const float* Wh, const float* bh, const float* Lh, const float* lbh,
    int4* __restrict__ wfrag, float* __restrict__ cvec){
  __shared__ u16 fl[6*4096];   // 48 KB
  int t = threadIdx.x;
  for(int idx=t; idx<12288; idx+=1024){
    int g = idx >> 12;
    int r = idx & 4095;
    int i = r>>6, j = r&63;
    const float* W = (g==0)?Wz:(g==1)?Wr:Wh;
    const float* L = (g==0)?Lz:(g==1)?Lr:Lh;
    float acc = 0.f;
    for(int k=0;k<64;k++) acc += W[i*64+k] * L[k*64+j];
    fl[(g*2+0)*4096 + r] = f2b(acc);
    fl[(g*2+1)*4096 + r] = f2b(L[(64+i)*64 + j]);
  }
  if(t < 192){
    int g = t>>6, j = t&63;
    const float* bb = (g==0)?bz:(g==1)?br:bh;
    const float* L  = (g==0)?Lz:(g==1)?Lr:Lh;
    const float* lb = (g==0)?lbz:(g==1)?lbr:lbh;
    float acc = lb[j];
    for(int k=0;k<64;k++) acc += bb[k] * L[k*64+j];
    cvec[t] = acc;
  }
  __syncthreads();
  for(int item=t; item<3072; item+=1024){
    int l = item & 63;
    int rest = item >> 6;       // m*8 + s*4 + tt
    int m = rest >> 3;
    int s = (rest >> 2) & 1;
    int tt = rest & 3;
    const u16* mat = fl + m*4096;
    int k0 = s*32 + (l>>4)*8;
    int n  = tt*16 + (l&15);
    union { u16 v[8]; int4 q; } tmp;
    #pragma unroll
    for(int j=0;j<8;j++) tmp.v[j] = mat[(k0+j)*64 + n];
    wfrag[item] = tmp.q;
  }
}

// ---------------- K5: transpose/cast x -> node-major bf16 x_t[n][b][64] ----------------
__global__ void xt_kernel(const float* __restrict__ x, ushort4* __restrict__ xt4){
  int t = blockIdx.x*256 + threadIdx.x;   // 0 .. NB*NN*16-1
  if(t >= NB*NN*16) return;
  int b = t / (NN*16);
  int rem = t - b*(NN*16);
  int n = rem >> 4;
  int c4 = rem & 15;
  float4 v = reinterpret_cast<const float4*>(x)[t];   // flat idx matches t exactly
  ushort4 o; o.x=f2b(v.x); o.y=f2b(v.y); o.z=f2b(v.z); o.w=f2b(v.w);
  xt4[(size_t)n*64 + b*16 + c4] = o;
}

// ---------------- K6: per-node aggregation (wave per node, contiguous 512B gather) ----
__global__ void agg_kernel(const ushort4* __restrict__ xt4, const int* __restrict__ row_off,
                           const int2* __restrict__ csr_ent, u16* __restrict__ agg){
  int wave = (blockIdx.x*blockDim.x + threadIdx.x) >> 6;
  int lane = threadIdx.x & 63;
  if(wave >= NN) return;
  int e0 = row_off[wave], e1 = row_off[wave+1];
  float a0=0.f, a1=0.f, a2=0.f, a3=0.f;
  for(int j=e0; j<e1; j++){
    int2 e = csr_ent[j];               // broadcast (same addr all lanes)
    float w = __int_as_float(e.y);
    ushort4 v = xt4[(size_t)e.x*64 + lane];
    a0 += w * b2f(v.x);
    a1 += w * b2f(v.y);
    a2 += w * b2f(v.z);
    a3 += w * b2f(v.w);
  }
  int b = lane >> 4, c4 = lane & 15;
  ushort4 o; o.x=f2b(a0); o.y=f2b(a1); o.z=f2b(a2); o.w=f2b(a3);
  reinterpret_cast<ushort4*>(agg)[((size_t)b*NN + wave)*16 + c4] = o;
}

// ---------------- K7: fused GRU gate kernel (MFMA) ----------------
#define LDW(m,s,t) __builtin_bit_cast(s16x8, wlds[((m)*8+(s)*4+(t))*64 + lane])

__global__ void __launch_bounds__(256) gate_kernel(
    const u16* __restrict__ agg, const float* __restrict__ H,
    const int4* __restrict__ wfrag, const float* __restrict__ cvec,
    const float* __restrict__ gate_w, const float* __restrict__ gate_b,
    float* __restrict__ Hnew, float* __restrict__ gatebuf)
{
  __shared__ int4 wlds[3072];                       // 48 KB fragged weights
  __shared__ __align__(16) u16 rlds[4][1152];       // per-wave R tile, 16 rows x 72 (padded)
  for(int i=threadIdx.x; i<3072; i+=256) wlds[i] = wfrag[i];
  __syncthreads();

  const int warp = threadIdx.x >> 6, lane = threadIdx.x & 63;
  const int mrow = lane & 15, quad = lane >> 4;
  const int tile = blockIdx.x*4 + warp;   // 0..4999
  const int r0 = tile*16;

  float czv[4], crv[4], chv[4], gwv[4];
  #pragma unroll
  for(int t=0;t<4;t++){
    czv[t] = cvec[t*16+mrow];
    crv[t] = cvec[64 + t*16+mrow];
    chv[t] = cvec[128 + t*16+mrow];
    gwv[t] = gate_w[t*16+mrow];
  }
  const float gb = gate_b[0];

  // A-fragments: agg (bf16) and H (f32 -> bf16)
  const int4* ap = reinterpret_cast<const int4*>(agg + (size_t)(r0+mrow)*64);
  s16x8 a0 = __builtin_bit_cast(s16x8, ap[quad]);
  s16x8 a1 = __builtin_bit_cast(s16x8, ap[4+quad]);

  const float* Hrow = H + (size_t)(r0+mrow)*64;
  union { f32x4 v4[2]; float f[8]; } u0, u1;
  u0.v4[0] = *reinterpret_cast<const f32x4*>(Hrow + quad*8);
  u0.v4[1] = *reinterpret_cast<const f32x4*>(Hrow + quad*8 + 4);
  u1.v4[0] = *reinterpret_cast<const f32x4*>(Hrow + 32 + quad*8);
  u1.v4[1] = *reinterpret_cast<const f32x4*>(Hrow + 32 + quad*8 + 4);
  s16x8 h0, h1;
  #pragma unroll
  for(int j=0;j<8;j++){
    h0[j] = (short)f2b(u0.f[j]);
    h1[j] = (short)f2b(u1.f[j]);
  }

  f32x4 Zc[4], Rc[4], Hc[4];
  #pragma unroll
  for(int t=0;t<4;t++){
    f32x4 acc = {0.f,0.f,0.f,0.f};
    acc = __builtin_amdgcn_mfma_f32_16x16x32_bf16(a0, LDW(0,0,t), acc, 0,0,0);
    acc = __builtin_amdgcn_mfma_f32_16x16x32_bf16(a1, LDW(0,1,t), acc, 0,0,0);
    acc = __builtin_amdgcn_mfma_f32_16x16x32_bf16(h0, LDW(1,0,t), acc, 0,0,0);
    acc = __builtin_amdgcn_mfma_f32_16x16x32_bf16(h1, LDW(1,1,t), acc, 0,0,0);
    Zc[t] = acc;
    f32x4 ar = {0.f,0.f,0.f,0.f};
    ar = __builtin_amdgcn_mfma_f32_16x16x32_bf16(a0, LDW(2,0,t), ar, 0,0,0);
    ar = __builtin_amdgcn_mfma_f32_16x16x32_bf16(a1, LDW(2,1,t), ar, 0,0,0);
    ar = __builtin_amdgcn_mfma_f32_16x16x32_bf16(h0, LDW(3,0,t), ar, 0,0,0);
    ar = __builtin_amdgcn_mfma_f32_16x16x32_bf16(h1, LDW(3,1,t), ar, 0,0,0);
    Rc[t] = ar;
    f32x4 ah = {0.f,0.f,0.f,0.f};
    ah = __builtin_amdgcn_mfma_f32_16x16x32_bf16(a0, LDW(4,0,t), ah, 0,0,0);
    ah = __builtin_amdgcn_mfma_f32_16x16x32_bf16(a1, LDW(4,1,t), ah, 0,0,0);
    Hc[t] = ah;
  }

  // sigmoid(R) -> LDS (C-layout write: row=quad*4+i, col=t*16+mrow)
  #pragma unroll
  for(int t=0;t<4;t++){
    #pragma unroll
    for(int i=0;i<4;i++){
      float r = 1.f/(1.f + __expf(-(Rc[t][i] + crv[t])));
      rlds[warp][(quad*4+i)*72 + t*16 + mrow] = f2b(r);
    }
  }
  __syncthreads();

  // read R back in A-layout (row=mrow, k=quad*8+j and +32), build H*R frags
  const u16* rp = &rlds[warp][mrow*72 + quad*8];
  int4 rv0 = *reinterpret_cast<const int4*>(rp);
  int4 rv1 = *reinterpret_cast<const int4*>(rp + 32);
  const u16* rv0p = reinterpret_cast<const u16*>(&rv0);
  const u16* rv1p = reinterpret_cast<const u16*>(&rv1);
  s16x8 hr0, hr1;
  #pragma unroll
  for(int j=0;j<8;j++){
    hr0[j] = (short)f2b(u0.f[j] * b2f(rv0p[j]));
    hr1[j] = (short)f2b(u1.f[j] * b2f(rv1p[j]));
  }
  #pragma unroll
  for(int t=0;t<4;t++){
    Hc[t] = __builtin_amdgcn_mfma_f32_16x16x32_bf16(hr0, LDW(5,0,t), Hc[t], 0,0,0);
    Hc[t] = __builtin_amdgcn_mfma_f32_16x16x32_bf16(hr1, LDW(5,1,t), Hc[t], 0,0,0);
  }

  // epilogue: Z, Ht, H_new, gate
  float ga[4] = {0.f,0.f,0.f,0.f};
  #pragma unroll
  for(int t=0;t<4;t++){
    #pragma unroll
    for(int i=0;i<4;i++){
      int row = r0 + quad*4 + i, col = t*16 + mrow;
      float z  = 1.f/(1.f + __expf(-(Zc[t][i] + czv[t])));
      float ht = tanhf(Hc[t][i] + chv[t]);
      float hv = H[(size_t)row*64 + col];
      float hn = z*hv + (1.f - z)*ht;
      Hnew[(size_t)row*64 + col] = hn;
      ga[i] += hn * gwv[t];
    }
  }
  #pragma unroll
  for(int i=0;i<4;i++){
    float v = ga[i];
    v += __shfl_xor(v, 1, 64);
    v += __shfl_xor(v, 2, 64);
    v += __shfl_xor(v, 4, 64);
    v += __shfl_xor(v, 8, 64);
    if(mrow == 0) gatebuf[r0 + quad*4 + i] = v + gb;
  }
}

// ---------------- K8: softmax stats per batch ----------------
__global__ void stats_kernel(const float* __restrict__ gatebuf, float* stats){
  __shared__ float red[1024];
  int b = blockIdx.x, t = threadIdx.x;
  float mx = -1e30f;
  for(int n=t; n<NN; n+=1024) mx = fmaxf(mx, gatebuf[b*NN+n]);
  red[t] = mx; __syncthreads();
  for(int off=512; off; off>>=1){ if(t<off) red[t]=fmaxf(red[t],red[t+off]); __syncthreads(); }
  mx = red[0]; __syncthreads();
  float s = 0.f;
  for(int n=t; n<NN; n+=1024) s += __expf(gatebuf[b*NN+n]-mx);
  red[t] = s; __syncthreads();
  for(int off=512; off; off>>=1){ if(t<off) red[t]+=red[t+off]; __syncthreads(); }
  if(t==0){ stats[b]=mx; stats[4+b]=1.f/red[0]; }
}

// ---------------- K9: attention-weighted sum -> y_acc ----------------
__global__ void pool_kernel(const float* __restrict__ Hnew, const float* __restrict__ gatebuf,
                            const float* __restrict__ stats, float* __restrict__ y_acc){
  int b = blockIdx.x >> 6;
  int chunk = blockIdx.x & 63;
  int warp = threadIdx.x >> 6, lane = threadIdx.x & 63;
  int wid = chunk*4 + warp;   // 0..255
  float mx = stats[b], inv = stats[4+b];
  float acc = 0.f;
  for(int n=wid; n<NN; n+=256){
    float w = __expf(gatebuf[b*NN+n]-mx) * inv;
    acc += w * Hnew[((size_t)b*NN + n)*64 + lane];
  }
  atomicAdd(&y_acc[b*64+lane], acc);
}

// ---------------- K10: head ----------------
__global__ void head_kernel(const float* __restrict__ y_acc,
                            const float* W1, const float* b1,
                            const float* W2, const float* b2, float* out){
  __shared__ float hid[4][64];
  int t = threadIdx.x;   // 256
  int b = t >> 6, d = t & 63;
  float acc = b1[d];
  for(int k=0;k<64;k++) acc += y_acc[b*64+k] * W1[k*64+d];
  hid[b][d] = fmaxf(acc, 0.f);
  __syncthreads();
  if(t < 128){
    int bb = t >> 5, o = t & 31;
    float a2 = b2[o];
    for(int d2=0; d2<64; d2++) a2 += hid[bb][d2] * W2[d2*32+o];
    out[bb*32+o] = a2;
  }
}

// ---------------- launch ----------------
extern "C" void kernel_launch(void* const* d_in, const int* in_sizes, int n_in,
                              void* d_out, int out_size, void* d_ws, size_t ws_size,
                              hipStream_t stream) {
  const float* x   = (const float*)d_in[0];
  const int*   ei  = (const int*)d_in[1];
  const float* ew  = (const float*)d_in[2];
  const float* H   = (const float*)d_in[3];
  const float* Wz = (const float*)d_in[4],  *bz = (const float*)d_in[5];
  const float* Wr = (const float*)d_in[6],  *br = (const float*)d_in[7];
  const float* Wh = (const float*)d_in[8],  *bh = (const float*)d_in[9];
  const float* Lz = (const float*)d_in[10], *lbz = (const float*)d_in[11];
  const float* Lr = (const float*)d_in[12], *lbr = (const float*)d_in[13];
  const float* Lh = (const float*)d_in[14], *lbh = (const float*)d_in[15];
  const float* gw = (const float*)d_in[16], *gbp = (const float*)d_in[17];
  const float* W1 = (const float*)d_in[18], *b1 = (const float*)d_in[19];
  const float* W2 = (const float*)d_in[20], *b2 = (const float*)d_in[21];

  float* y_out    = (float*)d_out;
  float* Hnew_out = (float*)d_out + 128;

  char* ws = (char*)d_ws;
  size_t off = 0;
  auto alloc = [&](size_t bytes)->char*{
    off = (off + 255) & ~(size_t)255;
    char* p = ws + off; off += bytes; return p;
  };
  float*   deg      = (float*)alloc(NN*4);
  float*   dinv     = (float*)alloc(NN*4);
  int*     cnt      = (int*)  alloc(NN*4);
  int*     cursor   = (int*)  alloc(NN*4);
  int*     row_off  = (int*)  alloc((NN+1)*4);
  int2*    csr_ent  = (int2*) alloc((size_t)NE*8);
  ushort4* xt4      = (ushort4*)alloc((size_t)NN*256*2);
  u16*     agg      = (u16*)  alloc((size_t)ROWS*64*2);
  int4*    wfrag    = (int4*) alloc(3072*16);
  float*   cvec     = (float*)alloc(192*4);
  float*   gatebuf  = (float*)alloc((size_t)ROWS*4);
  float*   stats    = (float*)alloc(8*4);
  float*   y_acc    = (float*)alloc(256*4);
  (void)ws_size; (void)n_in; (void)in_sizes; (void)out_size;

  zero_kernel<<<(NN+255)/256, 256, 0, stream>>>(deg, cnt, cursor, y_acc);
  hist_kernel<<<(NE+255)/256, 256, 0, stream>>>(ei, ew, deg, cnt);
  scan_kernel<<<1, 1024, 0, stream>>>(cnt, row_off, deg, dinv);
  fill_kernel<<<(NE+255)/256, 256, 0, stream>>>(ei, ew, dinv, row_off, cursor, csr_ent);
  prep_kernel<<<1, 1024, 0, stream>>>(Wz,bz,Lz,lbz, Wr,br,Lr,lbr, Wh,bh,Lh,lbh, wfrag, cvec);
  xt_kernel<<<(NB*NN*16 + 255)/256, 256, 0, stream>>>(x, xt4);
  agg_kernel<<<(NN+3)/4, 256, 0, stream>>>(xt4, row_off, csr_ent, agg);
  gate_kernel<<<ROWS/64, 256, 0, stream>>>(agg, H, wfrag, cvec, gw, gbp, Hnew_out, gatebuf);
  stats_kernel<<<4, 1024, 0, stream>>>(gatebuf, stats);
  pool_kernel<<<256, 256, 0, stream>>>(Hnew_out, gatebuf, stats, y_acc);
  head_kernel<<<1, 256, 0, stream>>>(y_acc, W1, b1, W2, b2, y_out);
}

// Round 5
// 338.500 us; speedup vs baseline: 1.1144x; 1.1144x over previous
//
#include <hip/hip_runtime.h>
#include <hip/hip_bf16.h>

typedef unsigned short u16;
typedef float f32x4 __attribute__((ext_vector_type(4)));
typedef short s16x8 __attribute__((ext_vector_type(8)));

#define NB 4
#define NN 20000
#define NE 320000
#define ROWS (NB*NN)          // 80000

__device__ __forceinline__ float b2f(u16 u){
  union{unsigned int i; float f;} v; v.i = ((unsigned int)u)<<16; return v.f;
}
__device__ __forceinline__ u16 f2b(float f){
  __hip_bfloat16 h = __float2bfloat16(f);
  return __builtin_bit_cast(u16, h);
}

// ---------------- K0: zero-init scratch ----------------
__global__ void zero_kernel(float* deg, int* cnt, int* cursor, float* y_acc){
  int i = blockIdx.x*blockDim.x + threadIdx.x;
  if(i < NN){ deg[i]=0.f; cnt[i]=0; cursor[i]=0; }
  if(i < 256) y_acc[i]=0.f;
}

// ---------------- K1: degree + count histogram ----------------
__global__ void hist_kernel(const int* __restrict__ ei, const float* __restrict__ ew,
                            float* deg, int* cnt){
  int e = blockIdx.x*blockDim.x + threadIdx.x;
  if(e >= NE) return;
  int d = ei[NE + e];
  atomicAdd(&deg[d], ew[e]);
  atomicAdd(&cnt[d], 1);
}

// ---------------- K2: exclusive prefix sum of cnt -> row_off, + dinv ----------------
__global__ void scan_kernel(const int* __restrict__ cnt, int* row_off,
                            const float* __restrict__ deg, float* dinv){
  __shared__ int part[1024];
  int t = threadIdx.x;
  const int chunk = (NN + 1023)/1024; // 20
  int s0 = t*chunk;
  int local = 0;
  for(int i=0;i<chunk;i++){
    int idx=s0+i;
    if(idx<NN){
      local += cnt[idx];
      float d = deg[idx];
      dinv[idx] = (d > 0.f) ? rsqrtf(fmaxf(d, 1e-12f)) : 0.f;
    }
  }
  part[t] = local;
  __syncthreads();
  for(int off=1; off<1024; off<<=1){
    int v = (t>=off) ? part[t-off] : 0;
    __syncthreads();
    part[t] += v;
    __syncthreads();
  }
  int base = (t>0) ? part[t-1] : 0;
  for(int i=0;i<chunk;i++){ int idx=s0+i; if(idx<NN){ row_off[idx]=base; base += cnt[idx]; } }
  if(t==1023) row_off[NN] = part[1023];
}

// ---------------- K3: CSR fill (interleaved {src, norm}) ----------------
__global__ void fill_kernel(const int* __restrict__ ei, const float* __restrict__ ew,
                            const float* __restrict__ dinv, const int* __restrict__ row_off,
                            int* cursor, int2* csr_ent){
  int e = blockIdx.x*blockDim.x + threadIdx.x;
  if(e >= NE) return;
  int s = ei[e], d = ei[NE + e];
  float nr = dinv[s] * ew[e] * dinv[d];
  int p = row_off[d] + atomicAdd(&cursor[d], 1);
  int2 ent; ent.x = s; ent.y = __float_as_int(nr);
  csr_ent[p] = ent;
}

// ---------------- K4: prep — 6 blocks, one per fused 64x64 matrix ----------------
// m=2g+0: Wg @ Lg_top   m=2g+1: Lg_bot   (g in {z,r,h})
// cvec[g*64+j] = bg @ Lg_top + lbg   (computed in even-m blocks)
// wfrag item (m,s,tt,lane): value[j] = mat_m[(s*32 + (lane>>4)*8 + j)*64 + tt*16 + (lane&15)]
__global__ void __launch_bounds__(256) prep6_kernel(
    const float* Wz, const float* bz, const float* Lz, const float* lbz,
    const float* Wr, const float* br, const float* Lr, const float* lbr,
    const float* Wh, const float* bh, const float* Lh, const float* lbh,
    int4* __restrict__ wfrag, float* __restrict__ cvec){
  int m = blockIdx.x;       // 0..5
  int g = m >> 1, half = m & 1;
  const float* W  = (g==0)?Wz:(g==1)?Wr:Wh;
  const float* L  = (g==0)?Lz:(g==1)?Lr:Lh;
  const float* bb = (g==0)?bz:(g==1)?br:bh;
  const float* lb = (g==0)?lbz:(g==1)?lbr:lbh;
  __shared__ __align__(16) float Wl[4096];
  __shared__ __align__(16) float Lt[4096];
  __shared__ __align__(16) float Pr[4096];
  int t = threadIdx.x;
  if(half == 0){
    // product: Pr = W @ L_top  (f32, same loop order as the R3-passing prep)
    for(int i=t; i<1024; i+=256){
      reinterpret_cast<float4*>(Wl)[i] = reinterpret_cast<const float4*>(W)[i];
      reinterpret_cast<float4*>(Lt)[i] = reinterpret_cast<const float4*>(L)[i];
    }
    __syncthreads();
    for(int q=0; q<16; q++){
      int idx = t + 256*q;
      int i = idx>>6, j = idx&63;   // i wave-uniform (idx>>6 = (t>>6)+4q), j stride-1
      float acc = 0.f;
      for(int k=0;k<64;k++) acc += Wl[i*64+k] * Lt[k*64+j];
      Pr[idx] = acc;
    }
    if(t < 64){
      float a = lb[t];
      for(int k=0;k<64;k++) a += bb[k]*Lt[k*64+t];
      cvec[g*64 + t] = a;
    }
  } else {
    // copy: Pr = L_bot
    for(int i=t; i<1024; i+=256)
      reinterpret_cast<float4*>(Pr)[i] = reinterpret_cast<const float4*>(L + 4096)[i];
  }
  __syncthreads();
  // emit this matrix's 512 wfrag items
  for(int it=t; it<512; it+=256){
    int l  = it & 63;
    int rl = it >> 6;          // s*4 + tt
    int s  = rl >> 2, tt = rl & 3;
    int k0 = s*32 + (l>>4)*8;
    int n  = tt*16 + (l&15);
    union { u16 v[8]; int4 q4; } tmp;
    #pragma unroll
    for(int j=0;j<8;j++) tmp.v[j] = f2b(Pr[(k0+j)*64 + n]);
    wfrag[m*512 + it] = tmp.q4;
  }
}

// ---------------- K5: transpose/cast x -> node-major bf16 x_t[n][b][64] ----------------
__global__ void xt_kernel(const float* __restrict__ x, ushort4* __restrict__ xt4){
  int t = blockIdx.x*256 + threadIdx.x;   // 0 .. NB*NN*16-1
  if(t >= NB*NN*16) return;
  int b = t / (NN*16);
  int rem = t - b*(NN*16);
  int n = rem >> 4;
  int c4 = rem & 15;
  float4 v = reinterpret_cast<const float4*>(x)[t];
  ushort4 o; o.x=f2b(v.x); o.y=f2b(v.y); o.z=f2b(v.z); o.w=f2b(v.w);
  xt4[(size_t)n*64 + b*16 + c4] = o;
}

// ---------------- K6: per-node aggregation (wave per node, contiguous 512B gather) ----
__global__ void agg_kernel(const ushort4* __restrict__ xt4, const int* __restrict__ row_off,
                           const int2* __restrict__ csr_ent, u16* __restrict__ agg){
  int wave = (blockIdx.x*blockDim.x + threadIdx.x) >> 6;
  int lane = threadIdx.x & 63;
  if(wave >= NN) return;
  int e0 = row_off[wave], e1 = row_off[wave+1];
  float a0=0.f, a1=0.f, a2=0.f, a3=0.f;
  for(int j=e0; j<e1; j++){
    int2 e = csr_ent[j];               // broadcast (same addr all lanes)
    float w = __int_as_float(e.y);
    ushort4 v = xt4[(size_t)e.x*64 + lane];
    a0 += w * b2f(v.x);
    a1 += w * b2f(v.y);
    a2 += w * b2f(v.z);
    a3 += w * b2f(v.w);
  }
  int b = lane >> 4, c4 = lane & 15;
  ushort4 o; o.x=f2b(a0); o.y=f2b(a1); o.z=f2b(a2); o.w=f2b(a3);
  reinterpret_cast<ushort4*>(agg)[((size_t)b*NN + wave)*16 + c4] = o;
}

// ---------------- K7: fused GRU gate kernel (MFMA) ----------------
#define LDW(m,s,t) __builtin_bit_cast(s16x8, wlds[((m)*8+(s)*4+(t))*64 + lane])

__global__ void __launch_bounds__(256) gate_kernel(
    const u16* __restrict__ agg, const float* __restrict__ H,
    const int4* __restrict__ wfrag, const float* __restrict__ cvec,
    const float* __restrict__ gate_w, const float* __restrict__ gate_b,
    float* __restrict__ Hnew, float* __restrict__ gatebuf)
{
  __shared__ int4 wlds[3072];                       // 48 KB fragged weights
  __shared__ __align__(16) u16 rlds[4][1152];       // per-wave R tile, 16 rows x 72 (padded)
  for(int i=threadIdx.x; i<3072; i+=256) wlds[i] = wfrag[i];
  __syncthreads();

  const int warp = threadIdx.x >> 6, lane = threadIdx.x & 63;
  const int mrow = lane & 15, quad = lane >> 4;
  const int tile = blockIdx.x*4 + warp;   // 0..4999
  const int r0 = tile*16;

  float czv[4], crv[4], chv[4], gwv[4];
  #pragma unroll
  for(int t=0;t<4;t++){
    czv[t] = cvec[t*16+mrow];
    crv[t] = cvec[64 + t*16+mrow];
    chv[t] = cvec[128 + t*16+mrow];
    gwv[t] = gate_w[t*16+mrow];
  }
  const float gb = gate_b[0];

  // A-fragments: agg (bf16) and H (f32 -> bf16)
  const int4* ap = reinterpret_cast<const int4*>(agg + (size_t)(r0+mrow)*64);
  s16x8 a0 = __builtin_bit_cast(s16x8, ap[quad]);
  s16x8 a1 = __builtin_bit_cast(s16x8, ap[4+quad]);

  const float* Hrow = H + (size_t)(r0+mrow)*64;
  union { f32x4 v4[2]; float f[8]; } u0, u1;
  u0.v4[0] = *reinterpret_cast<const f32x4*>(Hrow + quad*8);
  u0.v4[1] = *reinterpret_cast<const f32x4*>(Hrow + quad*8 + 4);
  u1.v4[0] = *reinterpret_cast<const f32x4*>(Hrow + 32 + quad*8);
  u1.v4[1] = *reinterpret_cast<const f32x4*>(Hrow + 32 + quad*8 + 4);
  s16x8 h0, h1;
  #pragma unroll
  for(int j=0;j<8;j++){
    h0[j] = (short)f2b(u0.f[j]);
    h1[j] = (short)f2b(u1.f[j]);
  }

  f32x4 Zc[4], Rc[4], Hc[4];
  #pragma unroll
  for(int t=0;t<4;t++){
    f32x4 acc = {0.f,0.f,0.f,0.f};
    acc = __builtin_amdgcn_mfma_f32_16x16x32_bf16(a0, LDW(0,0,t), acc, 0,0,0);
    acc = __builtin_amdgcn_mfma_f32_16x16x32_bf16(a1, LDW(0,1,t), acc, 0,0,0);
    acc = __builtin_amdgcn_mfma_f32_16x16x32_bf16(h0, LDW(1,0,t), acc, 0,0,0);
    acc = __builtin_amdgcn_mfma_f32_16x16x32_bf16(h1, LDW(1,1,t), acc, 0,0,0);
    Zc[t] = acc;
    f32x4 ar = {0.f,0.f,0.f,0.f};
    ar = __builtin_amdgcn_mfma_f32_16x16x32_bf16(a0, LDW(2,0,t), ar, 0,0,0);
    ar = __builtin_amdgcn_mfma_f32_16x16x32_bf16(a1, LDW(2,1,t), ar, 0,0,0);
    ar = __builtin_amdgcn_mfma_f32_16x16x32_bf16(h0, LDW(3,0,t), ar, 0,0,0);
    ar = __builtin_amdgcn_mfma_f32_16x16x32_bf16(h1, LDW(3,1,t), ar, 0,0,0);
    Rc[t] = ar;
    f32x4 ah = {0.f,0.f,0.f,0.f};
    ah = __builtin_amdgcn_mfma_f32_16x16x32_bf16(a0, LDW(4,0,t), ah, 0,0,0);
    ah = __builtin_amdgcn_mfma_f32_16x16x32_bf16(a1, LDW(4,1,t), ah, 0,0,0);
    Hc[t] = ah;
  }

  // sigmoid(R) -> LDS (C-layout write: row=quad*4+i, col=t*16+mrow)
  #pragma unroll
  for(int t=0;t<4;t++){
    #pragma unroll
    for(int i=0;i<4;i++){
      float r = 1.f/(1.f + __expf(-(Rc[t][i] + crv[t])));
      rlds[warp][(quad*4+i)*72 + t*16 + mrow] = f2b(r);
    }
  }
  __syncthreads();

  // read R back in A-layout (row=mrow, k=quad*8+j and +32), build H*R frags
  const u16* rp = &rlds[warp][mrow*72 + quad*8];
  int4 rv0 = *reinterpret_cast<const int4*>(rp);
  int4 rv1 = *reinterpret_cast<const int4*>(rp + 32);
  const u16* rv0p = reinterpret_cast<const u16*>(&rv0);
  const u16* rv1p = reinterpret_cast<const u16*>(&rv1);
  s16x8 hr0, hr1;
  #pragma unroll
  for(int j=0;j<8;j++){
    hr0[j] = (short)f2b(u0.f[j] * b2f(rv0p[j]));
    hr1[j] = (short)f2b(u1.f[j] * b2f(rv1p[j]));
  }
  #pragma unroll
  for(int t=0;t<4;t++){
    Hc[t] = __builtin_amdgcn_mfma_f32_16x16x32_bf16(hr0, LDW(5,0,t), Hc[t], 0,0,0);
    Hc[t] = __builtin_amdgcn_mfma_f32_16x16x32_bf16(hr1, LDW(5,1,t), Hc[t], 0,0,0);
  }

  // epilogue: Z, Ht, H_new, gate
  float ga[4] = {0.f,0.f,0.f,0.f};
  #pragma unroll
  for(int t=0;t<4;t++){
    #pragma unroll
    for(int i=0;i<4;i++){
      int row = r0 + quad*4 + i, col = t*16 + mrow;
      float z  = 1.f/(1.f + __expf(-(Zc[t][i] + czv[t])));
      float ht = tanhf(Hc[t][i] + chv[t]);
      float hv = H[(size_t)row*64 + col];
      float hn = z*hv + (1.f - z)*ht;
      Hnew[(size_t)row*64 + col] = hn;
      ga[i] += hn * gwv[t];
    }
  }
  #pragma unroll
  for(int i=0;i<4;i++){
    float v = ga[i];
    v += __shfl_xor(v, 1, 64);
    v += __shfl_xor(v, 2, 64);
    v += __shfl_xor(v, 4, 64);
    v += __shfl_xor(v, 8, 64);
    if(mrow == 0) gatebuf[r0 + quad*4 + i] = v + gb;
  }
}

// ---------------- K8: softmax stats per batch ----------------
__global__ void stats_kernel(const float* __restrict__ gatebuf, float* stats){
  __shared__ float red[1024];
  int b = blockIdx.x, t = threadIdx.x;
  float mx = -1e30f;
  for(int n=t; n<NN; n+=1024) mx = fmaxf(mx, gatebuf[b*NN+n]);
  red[t] = mx; __syncthreads();
  for(int off=512; off; off>>=1){ if(t<off) red[t]=fmaxf(red[t],red[t+off]); __syncthreads(); }
  mx = red[0]; __syncthreads();
  float s = 0.f;
  for(int n=t; n<NN; n+=1024) s += __expf(gatebuf[b*NN+n]-mx);
  red[t] = s; __syncthreads();
  for(int off=512; off; off>>=1){ if(t<off) red[t]+=red[t+off]; __syncthreads(); }
  if(t==0){ stats[b]=mx; stats[4+b]=1.f/red[0]; }
}

// ---------------- K9: attention-weighted sum -> y_acc ----------------
__global__ void pool_kernel(const float* __restrict__ Hnew, const float* __restrict__ gatebuf,
                            const float* __restrict__ stats, float* __restrict__ y_acc){
  int b = blockIdx.x >> 6;
  int chunk = blockIdx.x & 63;
  int warp = threadIdx.x >> 6, lane = threadIdx.x & 63;
  int wid = chunk*4 + warp;   // 0..255
  float mx = stats[b], inv = stats[4+b];
  float acc = 0.f;
  for(int n=wid; n<NN; n+=256){
    float w = __expf(gatebuf[b*NN+n]-mx) * inv;
    acc += w * Hnew[((size_t)b*NN + n)*64 + lane];
  }
  atomicAdd(&y_acc[b*64+lane], acc);
}

// ---------------- K10: head ----------------
__global__ void head_kernel(const float* __restrict__ y_acc,
                            const float* W1, const float* b1,
                            const float* W2, const float* b2, float* out){
  __shared__ float hid[4][64];
  int t = threadIdx.x;   // 256
  int b = t >> 6, d = t & 63;
  float acc = b1[d];
  for(int k=0;k<64;k++) acc += y_acc[b*64+k] * W1[k*64+d];
  hid[b][d] = fmaxf(acc, 0.f);
  __syncthreads();
  if(t < 128){
    int bb = t >> 5, o = t & 31;
    float a2 = b2[o];
    for(int d2=0; d2<64; d2++) a2 += hid[bb][d2] * W2[d2*32+o];
    out[bb*32+o] = a2;
  }
}

// ---------------- launch ----------------
extern "C" void kernel_launch(void* const* d_in, const int* in_sizes, int n_in,
                              void* d_out, int out_size, void* d_ws, size_t ws_size,
                              hipStream_t stream) {
  const float* x   = (const float*)d_in[0];
  const int*   ei  = (const int*)d_in[1];
  const float* ew  = (const float*)d_in[2];
  const float* H   = (const float*)d_in[3];
  const float* Wz = (const float*)d_in[4],  *bz = (const float*)d_in[5];
  const float* Wr = (const float*)d_in[6],  *br = (const float*)d_in[7];
  const float* Wh = (const float*)d_in[8],  *bh = (const float*)d_in[9];
  const float* Lz = (const float*)d_in[10], *lbz = (const float*)d_in[11];
  const float* Lr = (const float*)d_in[12], *lbr = (const float*)d_in[13];
  const float* Lh = (const float*)d_in[14], *lbh = (const float*)d_in[15];
  const float* gw = (const float*)d_in[16], *gbp = (const float*)d_in[17];
  const float* W1 = (const float*)d_in[18], *b1 = (const float*)d_in[19];
  const float* W2 = (const float*)d_in[20], *b2 = (const float*)d_in[21];

  float* y_out    = (float*)d_out;
  float* Hnew_out = (float*)d_out + 128;

  char* ws = (char*)d_ws;
  size_t off = 0;
  auto alloc = [&](size_t bytes)->char*{
    off = (off + 255) & ~(size_t)255;
    char* p = ws + off; off += bytes; return p;
  };
  float*   deg      = (float*)alloc(NN*4);
  float*   dinv     = (float*)alloc(NN*4);
  int*     cnt      = (int*)  alloc(NN*4);
  int*     cursor   = (int*)  alloc(NN*4);
  int*     row_off  = (int*)  alloc((NN+1)*4);
  int2*    csr_ent  = (int2*) alloc((size_t)NE*8);
  ushort4* xt4      = (ushort4*)alloc((size_t)NN*256*2);
  u16*     agg      = (u16*)  alloc((size_t)ROWS*64*2);
  int4*    wfrag    = (int4*) alloc(3072*16);
  float*   cvec     = (float*)alloc(192*4);
  float*   gatebuf  = (float*)alloc((size_t)ROWS*4);
  float*   stats    = (float*)alloc(8*4);
  float*   y_acc    = (float*)alloc(256*4);
  (void)ws_size; (void)n_in; (void)in_sizes; (void)out_size;

  zero_kernel<<<(NN+255)/256, 256, 0, stream>>>(deg, cnt, cursor, y_acc);
  hist_kernel<<<(NE+255)/256, 256, 0, stream>>>(ei, ew, deg, cnt);
  scan_kernel<<<1, 1024, 0, stream>>>(cnt, row_off, deg, dinv);
  fill_kernel<<<(NE+255)/256, 256, 0, stream>>>(ei, ew, dinv, row_off, cursor, csr_ent);
  prep6_kernel<<<6, 256, 0, stream>>>(Wz,bz,Lz,lbz, Wr,br,Lr,lbr, Wh,bh,Lh,lbh, wfrag, cvec);
  xt_kernel<<<(NB*NN*16 + 255)/256, 256, 0, stream>>>(x, xt4);
  agg_kernel<<<(NN+3)/4, 256, 0, stream>>>(xt4, row_off, csr_ent, agg);
  gate_kernel<<<ROWS/64, 256, 0, stream>>>(agg, H, wfrag, cvec, gw, gbp, Hnew_out, gatebuf);
  stats_kernel<<<4, 1024, 0, stream>>>(gatebuf, stats);
  pool_kernel<<<256, 256, 0, stream>>>(Hnew_out, gatebuf, stats, y_acc);
  head_kernel<<<1, 256, 0, stream>>>(y_acc, W1, b1, W2, b2, y_out);
}

// Round 6
// 298.138 us; speedup vs baseline: 1.2653x; 1.1354x over previous
//
#include <hip/hip_runtime.h>
#include <hip/hip_bf16.h>

typedef unsigned short u16;
typedef float f32x4 __attribute__((ext_vector_type(4)));
typedef short s16x8 __attribute__((ext_vector_type(8)));

#define NB 4
#define NN 20000
#define NE 320000
#define ROWS (NB*NN)          // 80000

__device__ __forceinline__ float b2f(u16 u){
  union{unsigned int i; float f;} v; v.i = ((unsigned int)u)<<16; return v.f;
}
__device__ __forceinline__ u16 f2b(float f){
  __hip_bfloat16 h = __float2bfloat16(f);
  return __builtin_bit_cast(u16, h);
}

// ---------------- K0: zero-init scratch ----------------
__global__ void zero_kernel(float* deg, int* cnt, int* cursor, float* y_acc){
  int i = blockIdx.x*blockDim.x + threadIdx.x;
  if(i < NN){ deg[i]=0.f; cnt[i]=0; cursor[i]=0; }
  if(i < 256) y_acc[i]=0.f;
}

// ---------------- K1: degree + count histogram ----------------
__global__ void hist_kernel(const int* __restrict__ ei, const float* __restrict__ ew,
                            float* deg, int* cnt){
  int e = blockIdx.x*blockDim.x + threadIdx.x;
  if(e >= NE) return;
  int d = ei[NE + e];
  atomicAdd(&deg[d], ew[e]);
  atomicAdd(&cnt[d], 1);
}

// ---------------- K2a: parallel scan pass A (20 blocks x 1024) ----------------
// local exclusive prefix of cnt -> row_off, block totals -> blocksum, + dinv
__global__ void __launch_bounds__(1024) scanA_kernel(
    const int* __restrict__ cnt, const float* __restrict__ deg,
    float* __restrict__ dinv, int* __restrict__ row_off, int* __restrict__ blocksum){
  int b = blockIdx.x, t = threadIdx.x;
  int i = b*1024 + t;
  int v = (i < NN) ? cnt[i] : 0;
  if(i < NN){
    float d = deg[i];
    dinv[i] = (d > 0.f) ? rsqrtf(fmaxf(d, 1e-12f)) : 0.f;
  }
  int lane = t & 63, wid = t >> 6;
  int x = v;
  #pragma unroll
  for(int off=1; off<64; off<<=1){
    int y = __shfl_up(x, off, 64);
    if(lane >= off) x += y;
  }
  __shared__ int swv[16];
  if(lane == 63) swv[wid] = x;
  __syncthreads();
  if(wid == 0){
    int wv = (lane < 16) ? swv[lane] : 0;
    #pragma unroll
    for(int off=1; off<16; off<<=1){
      int y = __shfl_up(wv, off, 64);
      if(lane >= off) wv += y;
    }
    if(lane < 16) swv[lane] = wv;
  }
  __syncthreads();
  int woff = (wid > 0) ? swv[wid-1] : 0;
  int incl = x + woff;
  if(i < NN) row_off[i] = incl - v;        // local exclusive prefix
  if(t == 1023) blocksum[b] = incl;
}

// ---------------- K2b: add block offsets (in-place, same thread->same i) ----------
__global__ void __launch_bounds__(1024) scanB_kernel(
    int* __restrict__ row_off, const int* __restrict__ blocksum){
  int b = blockIdx.x, t = threadIdx.x;
  int i = b*1024 + t;
  int off = 0;
  for(int k=0;k<b;k++) off += blocksum[k];   // <=19 broadcast loads
  if(i < NN) row_off[i] += off;
  if(i == 0) row_off[NN] = NE;
}

// ---------------- K3: CSR fill (interleaved {src, norm}) ----------------
__global__ void fill_kernel(const int* __restrict__ ei, const float* __restrict__ ew,
                            const float* __restrict__ dinv, const int* __restrict__ row_off,
                            int* cursor, int2* csr_ent){
  int e = blockIdx.x*blockDim.x + threadIdx.x;
  if(e >= NE) return;
  int s = ei[e], d = ei[NE + e];
  float nr = dinv[s] * ew[e] * dinv[d];
  int p = row_off[d] + atomicAdd(&cursor[d], 1);
  int2 ent; ent.x = s; ent.y = __float_as_int(nr);
  csr_ent[p] = ent;
}

// ---------------- K4: prep — 6 blocks, one per fused 64x64 matrix ----------------
// m=2g+0: Wg @ Lg_top   m=2g+1: Lg_bot   (g in {z,r,h})
// cvec[g*64+j] = bg @ Lg_top + lbg   (computed in even-m blocks)
// wfrag item (m,s,tt,lane): value[j] = mat_m[(s*32 + (lane>>4)*8 + j)*64 + tt*16 + (lane&15)]
__global__ void __launch_bounds__(256) prep6_kernel(
    const float* Wz, const float* bz, const float* Lz, const float* lbz,
    const float* Wr, const float* br, const float* Lr, const float* lbr,
    const float* Wh, const float* bh, const float* Lh, const float* lbh,
    int4* __restrict__ wfrag, float* __restrict__ cvec){
  int m = blockIdx.x;       // 0..5
  int g = m >> 1, half = m & 1;
  const float* W  = (g==0)?Wz:(g==1)?Wr:Wh;
  const float* L  = (g==0)?Lz:(g==1)?Lr:Lh;
  const float* bb = (g==0)?bz:(g==1)?br:bh;
  const float* lb = (g==0)?lbz:(g==1)?lbr:lbh;
  __shared__ __align__(16) float Wl[4096];
  __shared__ __align__(16) float Lt[4096];
  __shared__ __align__(16) float Pr[4096];
  int t = threadIdx.x;
  if(half == 0){
    for(int i=t; i<1024; i+=256){
      reinterpret_cast<float4*>(Wl)[i] = reinterpret_cast<const float4*>(W)[i];
      reinterpret_cast<float4*>(Lt)[i] = reinterpret_cast<const float4*>(L)[i];
    }
    __syncthreads();
    for(int q=0; q<16; q++){
      int idx = t + 256*q;
      int i = idx>>6, j = idx&63;
      float acc = 0.f;
      for(int k=0;k<64;k++) acc += Wl[i*64+k] * Lt[k*64+j];
      Pr[idx] = acc;
    }
    if(t < 64){
      float a = lb[t];
      for(int k=0;k<64;k++) a += bb[k]*Lt[k*64+t];
      cvec[g*64 + t] = a;
    }
  } else {
    for(int i=t; i<1024; i+=256)
      reinterpret_cast<float4*>(Pr)[i] = reinterpret_cast<const float4*>(L + 4096)[i];
  }
  __syncthreads();
  for(int it=t; it<512; it+=256){
    int l  = it & 63;
    int rl = it >> 6;          // s*4 + tt
    int s  = rl >> 2, tt = rl & 3;
    int k0 = s*32 + (l>>4)*8;
    int n  = tt*16 + (l&15);
    union { u16 v[8]; int4 q4; } tmp;
    #pragma unroll
    for(int j=0;j<8;j++) tmp.v[j] = f2b(Pr[(k0+j)*64 + n]);
    wfrag[m*512 + it] = tmp.q4;
  }
}

// ---------------- K5: transpose/cast x -> node-major bf16 x_t[n][b][64] ----------------
__global__ void xt_kernel(const float* __restrict__ x, ushort4* __restrict__ xt4){
  int t = blockIdx.x*256 + threadIdx.x;   // 0 .. NB*NN*16-1
  if(t >= NB*NN*16) return;
  int b = t / (NN*16);
  int rem = t - b*(NN*16);
  int n = rem >> 4;
  int c4 = rem & 15;
  float4 v = reinterpret_cast<const float4*>(x)[t];
  ushort4 o; o.x=f2b(v.x); o.y=f2b(v.y); o.z=f2b(v.z); o.w=f2b(v.w);
  xt4[(size_t)n*64 + b*16 + c4] = o;
}

// ---------------- K6: per-node aggregation (wave per node, contiguous 512B gather) ----
__global__ void agg_kernel(const ushort4* __restrict__ xt4, const int* __restrict__ row_off,
                           const int2* __restrict__ csr_ent, u16* __restrict__ agg){
  int wave = (blockIdx.x*blockDim.x + threadIdx.x) >> 6;
  int lane = threadIdx.x & 63;
  if(wave >= NN) return;
  int e0 = row_off[wave], e1 = row_off[wave+1];
  float a0=0.f, a1=0.f, a2=0.f, a3=0.f;
  for(int j=e0; j<e1; j++){
    int2 e = csr_ent[j];               // broadcast (same addr all lanes)
    float w = __int_as_float(e.y);
    ushort4 v = xt4[(size_t)e.x*64 + lane];
    a0 += w * b2f(v.x);
    a1 += w * b2f(v.y);
    a2 += w * b2f(v.z);
    a3 += w * b2f(v.w);
  }
  int b = lane >> 4, c4 = lane & 15;
  ushort4 o; o.x=f2b(a0); o.y=f2b(a1); o.z=f2b(a2); o.w=f2b(a3);
  reinterpret_cast<ushort4*>(agg)[((size_t)b*NN + wave)*16 + c4] = o;
}

// ---------------- K7: fused GRU gate kernel (MFMA) ----------------
#define LDW(m,s,t) __builtin_bit_cast(s16x8, wlds[((m)*8+(s)*4+(t))*64 + lane])

__global__ void __launch_bounds__(256) gate_kernel(
    const u16* __restrict__ agg, const float* __restrict__ H,
    const int4* __restrict__ wfrag, const float* __restrict__ cvec,
    const float* __restrict__ gate_w, const float* __restrict__ gate_b,
    float* __restrict__ Hnew, float* __restrict__ gatebuf)
{
  __shared__ int4 wlds[3072];                       // 48 KB fragged weights
  __shared__ __align__(16) u16 rlds[4][1152];       // per-wave R tile, 16 rows x 72 (padded)
  for(int i=threadIdx.x; i<3072; i+=256) wlds[i] = wfrag[i];
  __syncthreads();

  const int warp = threadIdx.x >> 6, lane = threadIdx.x & 63;
  const int mrow = lane & 15, quad = lane >> 4;
  const int tile = blockIdx.x*4 + warp;   // 0..4999
  const int r0 = tile*16;

  float czv[4], crv[4], chv[4], gwv[4];
  #pragma unroll
  for(int t=0;t<4;t++){
    czv[t] = cvec[t*16+mrow];
    crv[t] = cvec[64 + t*16+mrow];
    chv[t] = cvec[128 + t*16+mrow];
    gwv[t] = gate_w[t*16+mrow];
  }
  const float gb = gate_b[0];

  // A-fragments: agg (bf16) and H (f32 -> bf16)
  const int4* ap = reinterpret_cast<const int4*>(agg + (size_t)(r0+mrow)*64);
  s16x8 a0 = __builtin_bit_cast(s16x8, ap[quad]);
  s16x8 a1 = __builtin_bit_cast(s16x8, ap[4+quad]);

  const float* Hrow = H + (size_t)(r0+mrow)*64;
  union { f32x4 v4[2]; float f[8]; } u0, u1;
  u0.v4[0] = *reinterpret_cast<const f32x4*>(Hrow + quad*8);
  u0.v4[1] = *reinterpret_cast<const f32x4*>(Hrow + quad*8 + 4);
  u1.v4[0] = *reinterpret_cast<const f32x4*>(Hrow + 32 + quad*8);
  u1.v4[1] = *reinterpret_cast<const f32x4*>(Hrow + 32 + quad*8 + 4);
  s16x8 h0, h1;
  #pragma unroll
  for(int j=0;j<8;j++){
    h0[j] = (short)f2b(u0.f[j]);
    h1[j] = (short)f2b(u1.f[j]);
  }

  f32x4 Zc[4], Rc[4], Hc[4];
  #pragma unroll
  for(int t=0;t<4;t++){
    f32x4 acc = {0.f,0.f,0.f,0.f};
    acc = __builtin_amdgcn_mfma_f32_16x16x32_bf16(a0, LDW(0,0,t), acc, 0,0,0);
    acc = __builtin_amdgcn_mfma_f32_16x16x32_bf16(a1, LDW(0,1,t), acc, 0,0,0);
    acc = __builtin_amdgcn_mfma_f32_16x16x32_bf16(h0, LDW(1,0,t), acc, 0,0,0);
    acc = __builtin_amdgcn_mfma_f32_16x16x32_bf16(h1, LDW(1,1,t), acc, 0,0,0);
    Zc[t] = acc;
    f32x4 ar = {0.f,0.f,0.f,0.f};
    ar = __builtin_amdgcn_mfma_f32_16x16x32_bf16(a0, LDW(2,0,t), ar, 0,0,0);
    ar = __builtin_amdgcn_mfma_f32_16x16x32_bf16(a1, LDW(2,1,t), ar, 0,0,0);
    ar = __builtin_amdgcn_mfma_f32_16x16x32_bf16(h0, LDW(3,0,t), ar, 0,0,0);
    ar = __builtin_amdgcn_mfma_f32_16x16x32_bf16(h1, LDW(3,1,t), ar, 0,0,0);
    Rc[t] = ar;
    f32x4 ah = {0.f,0.f,0.f,0.f};
    ah = __builtin_amdgcn_mfma_f32_16x16x32_bf16(a0, LDW(4,0,t), ah, 0,0,0);
    ah = __builtin_amdgcn_mfma_f32_16x16x32_bf16(a1, LDW(4,1,t), ah, 0,0,0);
    Hc[t] = ah;
  }

  // sigmoid(R) -> LDS (C-layout write: row=quad*4+i, col=t*16+mrow)
  #pragma unroll
  for(int t=0;t<4;t++){
    #pragma unroll
    for(int i=0;i<4;i++){
      float r = 1.f/(1.f + __expf(-(Rc[t][i] + crv[t])));
      rlds[warp][(quad*4+i)*72 + t*16 + mrow] = f2b(r);
    }
  }
  __syncthreads();

  // read R back in A-layout (row=mrow, k=quad*8+j and +32), build H*R frags
  const u16* rp = &rlds[warp][mrow*72 + quad*8];
  int4 rv0 = *reinterpret_cast<const int4*>(rp);
  int4 rv1 = *reinterpret_cast<const int4*>(rp + 32);
  const u16* rv0p = reinterpret_cast<const u16*>(&rv0);
  const u16* rv1p = reinterpret_cast<const u16*>(&rv1);
  s16x8 hr0, hr1;
  #pragma unroll
  for(int j=0;j<8;j++){
    hr0[j] = (short)f2b(u0.f[j] * b2f(rv0p[j]));
    hr1[j] = (short)f2b(u1.f[j] * b2f(rv1p[j]));
  }
  #pragma unroll
  for(int t=0;t<4;t++){
    Hc[t] = __builtin_amdgcn_mfma_f32_16x16x32_bf16(hr0, LDW(5,0,t), Hc[t], 0,0,0);
    Hc[t] = __builtin_amdgcn_mfma_f32_16x16x32_bf16(hr1, LDW(5,1,t), Hc[t], 0,0,0);
  }

  // epilogue: Z, Ht, H_new, gate
  float ga[4] = {0.f,0.f,0.f,0.f};
  #pragma unroll
  for(int t=0;t<4;t++){
    #pragma unroll
    for(int i=0;i<4;i++){
      int row = r0 + quad*4 + i, col = t*16 + mrow;
      float z  = 1.f/(1.f + __expf(-(Zc[t][i] + czv[t])));
      float ht = tanhf(Hc[t][i] + chv[t]);
      float hv = H[(size_t)row*64 + col];
      float hn = z*hv + (1.f - z)*ht;
      Hnew[(size_t)row*64 + col] = hn;
      ga[i] += hn * gwv[t];
    }
  }
  #pragma unroll
  for(int i=0;i<4;i++){
    float v = ga[i];
    v += __shfl_xor(v, 1, 64);
    v += __shfl_xor(v, 2, 64);
    v += __shfl_xor(v, 4, 64);
    v += __shfl_xor(v, 8, 64);
    if(mrow == 0) gatebuf[r0 + quad*4 + i] = v + gb;
  }
}

// ---------------- K8: softmax stats per batch ----------------
__global__ void stats_kernel(const float* __restrict__ gatebuf, float* stats){
  __shared__ float red[1024];
  int b = blockIdx.x, t = threadIdx.x;
  float mx = -1e30f;
  for(int n=t; n<NN; n+=1024) mx = fmaxf(mx, gatebuf[b*NN+n]);
  red[t] = mx; __syncthreads();
  for(int off=512; off; off>>=1){ if(t<off) red[t]=fmaxf(red[t],red[t+off]); __syncthreads(); }
  mx = red[0]; __syncthreads();
  float s = 0.f;
  for(int n=t; n<NN; n+=1024) s += __expf(gatebuf[b*NN+n]-mx);
  red[t] = s; __syncthreads();
  for(int off=512; off; off>>=1){ if(t<off) red[t]+=red[t+off]; __syncthreads(); }
  if(t==0){ stats[b]=mx; stats[4+b]=1.f/red[0]; }
}

// ---------------- K9: attention-weighted sum -> y_acc ----------------
__global__ void pool_kernel(const float* __restrict__ Hnew, const float* __restrict__ gatebuf,
                            const float* __restrict__ stats, float* __restrict__ y_acc){
  int b = blockIdx.x >> 6;
  int chunk = blockIdx.x & 63;
  int warp = threadIdx.x >> 6, lane = threadIdx.x & 63;
  int wid = chunk*4 + warp;   // 0..255
  float mx = stats[b], inv = stats[4+b];
  float acc = 0.f;
  for(int n=wid; n<NN; n+=256){
    float w = __expf(gatebuf[b*NN+n]-mx) * inv;
    acc += w * Hnew[((size_t)b*NN + n)*64 + lane];
  }
  atomicAdd(&y_acc[b*64+lane], acc);
}

// ---------------- K10: head ----------------
__global__ void head_kernel(const float* __restrict__ y_acc,
                            const float* W1, const float* b1,
                            const float* W2, const float* b2, float* out){
  __shared__ float hid[4][64];
  int t = threadIdx.x;   // 256
  int b = t >> 6, d = t & 63;
  float acc = b1[d];
  for(int k=0;k<64;k++) acc += y_acc[b*64+k] * W1[k*64+d];
  hid[b][d] = fmaxf(acc, 0.f);
  __syncthreads();
  if(t < 128){
    int bb = t >> 5, o = t & 31;
    float a2 = b2[o];
    for(int d2=0; d2<64; d2++) a2 += hid[bb][d2] * W2[d2*32+o];
    out[bb*32+o] = a2;
  }
}

// ---------------- launch ----------------
extern "C" void kernel_launch(void* const* d_in, const int* in_sizes, int n_in,
                              void* d_out, int out_size, void* d_ws, size_t ws_size,
                              hipStream_t stream) {
  const float* x   = (const float*)d_in[0];
  const int*   ei  = (const int*)d_in[1];
  const float* ew  = (const float*)d_in[2];
  const float* H   = (const float*)d_in[3];
  const float* Wz = (const float*)d_in[4],  *bz = (const float*)d_in[5];
  const float* Wr = (const float*)d_in[6],  *br = (const float*)d_in[7];
  const float* Wh = (const float*)d_in[8],  *bh = (const float*)d_in[9];
  const float* Lz = (const float*)d_in[10], *lbz = (const float*)d_in[11];
  const float* Lr = (const float*)d_in[12], *lbr = (const float*)d_in[13];
  const float* Lh = (const float*)d_in[14], *lbh = (const float*)d_in[15];
  const float* gw = (const float*)d_in[16], *gbp = (const float*)d_in[17];
  const float* W1 = (const float*)d_in[18], *b1 = (const float*)d_in[19];
  const float* W2 = (const float*)d_in[20], *b2 = (const float*)d_in[21];

  float* y_out    = (float*)d_out;
  float* Hnew_out = (float*)d_out + 128;

  char* ws = (char*)d_ws;
  size_t off = 0;
  auto alloc = [&](size_t bytes)->char*{
    off = (off + 255) & ~(size_t)255;
    char* p = ws + off; off += bytes; return p;
  };
  float*   deg      = (float*)alloc(NN*4);
  float*   dinv     = (float*)alloc(NN*4);
  int*     cnt      = (int*)  alloc(NN*4);
  int*     cursor   = (int*)  alloc(NN*4);
  int*     row_off  = (int*)  alloc((NN+1)*4);
  int2*    csr_ent  = (int2*) alloc((size_t)NE*8);
  ushort4* xt4      = (ushort4*)alloc((size_t)NN*256*2);
  u16*     agg      = (u16*)  alloc((size_t)ROWS*64*2);
  int4*    wfrag    = (int4*) alloc(3072*16);
  float*   cvec     = (float*)alloc(192*4);
  float*   gatebuf  = (float*)alloc((size_t)ROWS*4);
  float*   stats    = (float*)alloc(8*4);
  float*   y_acc    = (float*)alloc(256*4);
  int*     blocksum = (int*)  alloc(32*4);
  (void)ws_size; (void)n_in; (void)in_sizes; (void)out_size;

  zero_kernel<<<(NN+255)/256, 256, 0, stream>>>(deg, cnt, cursor, y_acc);
  hist_kernel<<<(NE+255)/256, 256, 0, stream>>>(ei, ew, deg, cnt);
  scanA_kernel<<<20, 1024, 0, stream>>>(cnt, deg, dinv, row_off, blocksum);
  scanB_kernel<<<20, 1024, 0, stream>>>(row_off, blocksum);
  fill_kernel<<<(NE+255)/256, 256, 0, stream>>>(ei, ew, dinv, row_off, cursor, csr_ent);
  prep6_kernel<<<6, 256, 0, stream>>>(Wz,bz,Lz,lbz, Wr,br,Lr,lbr, Wh,bh,Lh,lbh, wfrag, cvec);
  xt_kernel<<<(NB*NN*16 + 255)/256, 256, 0, stream>>>(x, xt4);
  agg_kernel<<<(NN+3)/4, 256, 0, stream>>>(xt4, row_off, csr_ent, agg);
  gate_kernel<<<ROWS/64, 256, 0, stream>>>(agg, H, wfrag, cvec, gw, gbp, Hnew_out, gatebuf);
  stats_kernel<<<4, 1024, 0, stream>>>(gatebuf, stats);
  pool_kernel<<<256, 256, 0, stream>>>(Hnew_out, gatebuf, stats, y_acc);
  head_kernel<<<1, 256, 0, stream>>>(y_acc, W1, b1, W2, b2, y_out);
}